// Round 4
// baseline (414.200 us; speedup 1.0000x reference)
//
#include <hip/hip_runtime.h>

#define TT 128
#define SS 512
#define START_TAG 126
#define STOP_TAG 127
#define LOG2E 1.4426950408889634f
#define LN2   0.6931471805599453f
#define CBITS 12

typedef float f32x4 __attribute__((ext_vector_type(4)));
typedef __fp16 f16x8 __attribute__((ext_vector_type(8)));
typedef __fp16 h2    __attribute__((ext_vector_type(2)));
typedef unsigned int u32;
typedef unsigned int u32x2 __attribute__((ext_vector_type(2)));
typedef unsigned int u32x4 __attribute__((ext_vector_type(4)));

__device__ __forceinline__ float ex2(float x) { return __builtin_amdgcn_exp2f(x); }   // 2^x
__device__ __forceinline__ float lg2(float x) { return __builtin_amdgcn_logf(x); }    // log2
__device__ __forceinline__ float exn(float x) { return __builtin_amdgcn_exp2f(x * LOG2E); } // e^x

__device__ __forceinline__ h2 h2max(h2 a, h2 b) {
    h2 r;
    r[0] = a[0] > b[0] ? a[0] : b[0];
    r[1] = a[1] > b[1] ? a[1] : b[1];
    return r;   // compiles to v_pk_max_f16
}
__device__ __forceinline__ float wave_max(float v) {
#pragma unroll
    for (int off = 32; off >= 1; off >>= 1) v = fmaxf(v, __shfl_xor(v, off));
    return v;
}
__device__ __forceinline__ float wave_sum(float v) {
#pragma unroll
    for (int off = 32; off >= 1; off >>= 1) v += __shfl_xor(v, off);
    return v;
}

// ---------------- pre-pass: ef[b][s][tag] = (f16) exp(feats) ----------------
__global__ __launch_bounds__(256) void exp_feats_kernel(
    const float* __restrict__ feats, __fp16* __restrict__ ef)
{
    size_t i = ((size_t)blockIdx.x * 256 + threadIdx.x) * 8;
    f32x4 a = *(const f32x4*)(feats + i);
    f32x4 b = *(const f32x4*)(feats + i + 4);
    h2 r0 = __builtin_amdgcn_cvt_pkrtz(exn(a[0]), exn(a[1]));
    h2 r1 = __builtin_amdgcn_cvt_pkrtz(exn(a[2]), exn(a[3]));
    h2 r2 = __builtin_amdgcn_cvt_pkrtz(exn(b[0]), exn(b[1]));
    h2 r3 = __builtin_amdgcn_cvt_pkrtz(exn(b[2]), exn(b[3]));
    u32x4 pk;
    pk[0] = __builtin_bit_cast(u32, r0);
    pk[1] = __builtin_bit_cast(u32, r1);
    pk[2] = __builtin_bit_cast(u32, r2);
    pk[3] = __builtin_bit_cast(u32, r3);
    *(u32x4*)(ef + i) = pk;
}

// ---------------- ef load (depth-3 pipeline buffer) ----------------
// Buffer tt holds ef[tags 16tt+4h .. +3] as 2 packed u32 (matches D rows).
template<bool PRE>
__device__ __forceinline__ void load_ef(const char*& pef, int sstep, u32x2 (&d)[8])
{
    if constexpr (PRE) {
#pragma unroll
        for (int tt = 0; tt < 8; ++tt) d[tt] = *(const u32x2*)(pef + 32 * tt);
    } else {
#pragma unroll
        for (int tt = 0; tt < 8; ++tt) {
            f32x4 v = *(const f32x4*)(pef + 64 * tt);
            h2 a = __builtin_amdgcn_cvt_pkrtz(exn(v[0]), exn(v[1]));
            h2 b = __builtin_amdgcn_cvt_pkrtz(exn(v[2]), exn(v[3]));
            d[tt][0] = __builtin_bit_cast(u32, a);
            d[tt][1] = __builtin_bit_cast(u32, b);
        }
    }
    pef += sstep;
}

// ---------------- one recurrence step for 16 chains ----------------
// k-map (shared by A-init, seed, and B-formation):
//   k(q,h,j) = 32q + 16*(j>=4) + 4h + (j&3)
// Scale: s = ceil(lg2(prev post-scale B colmax)) + CBITS. Lag-1 feedback on the
// POST-scale max is unconditionally stable (m_i = g_i - CBITS, no recurrence),
// unlike raw-D feedback (round-1 oscillator). The colmax shfls overlap the
// next step's MFMA phase -> nothing cross-lane on the critical path.
// Exact power-of-2 scale, integer bookkeeping in Mint (per-column, uniform
// across the 4 h-lanes of a column since shfl-reduced).
__device__ __forceinline__ void chain_step(
    const f16x8 (&E)[8][4], f16x8 (&Bv)[4], const u32x2 (&ef)[8],
    int& Mint, float& mprev)
{
    int s = ((__float_as_int(fmaxf(mprev, 1e-30f)) >> 23) & 0xff) - 126 + CBITS;
    s = s < -120 ? -120 : (s > 120 ? 120 : s);
    Mint += s;
    const float scf = __int_as_float((127 - s) << 23);    // exact 2^-s

    const f32x4 z = {0.f, 0.f, 0.f, 0.f};
    f32x4 acc[8];
#pragma unroll
    for (int tt = 0; tt < 8; ++tt)
        acc[tt] = __builtin_amdgcn_mfma_f32_16x16x32_f16(E[tt][0], Bv[0], z, 0, 0, 0);
#pragma unroll
    for (int q = 1; q < 4; ++q)
#pragma unroll
        for (int tt = 0; tt < 8; ++tt)
            acc[tt] = __builtin_amdgcn_mfma_f32_16x16x32_f16(E[tt][q], Bv[q], acc[tt], 0, 0, 0);

    h2 pkm = { (__fp16)0.f, (__fp16)0.f };
    u32 prev0 = 0, prev1 = 0;
#pragma unroll
    for (int tt = 0; tt < 8; ++tt) {
        h2 p01 = __builtin_amdgcn_cvt_pkrtz(acc[tt][0] * scf, acc[tt][1] * scf);
        h2 p23 = __builtin_amdgcn_cvt_pkrtz(acc[tt][2] * scf, acc[tt][3] * scf);
        p01 *= __builtin_bit_cast(h2, ef[tt][0]);   // emission, packed f16
        p23 *= __builtin_bit_cast(h2, ef[tt][1]);
        pkm = h2max(pkm, h2max(p01, p23));          // post-scale B colmax tracking
        if ((tt & 1) == 0) {
            prev0 = __builtin_bit_cast(u32, p01);
            prev1 = __builtin_bit_cast(u32, p23);
        } else {
            u32x4 bv = { prev0, prev1,
                         __builtin_bit_cast(u32, p01), __builtin_bit_cast(u32, p23) };
            Bv[tt >> 1] = __builtin_bit_cast(f16x8, bv);   // B formation, in-lane
        }
    }
    float mm = fmaxf((float)pkm[0], (float)pkm[1]);
    mm = fmaxf(mm, __shfl_xor(mm, 16));     // completes under next step's MFMAs
    mm = fmaxf(mm, __shfl_xor(mm, 32));
    mprev = mm;
}

// 8 blocks x 256 threads. Block k: batches 32k..32k+31.
//  w0: fwd chains (batches +0..15)  w1: fwd (+16..31)
//  w2: bwd chains (+0..15)          w3: bwd (+16..31)
// launch_bounds(256,2): <=256-reg budget -> arch-VGPR residency (no accvgpr
// churn; the round-3 156-VGPR/2x-inflation pathology). Footprint ~234.
template<bool PRE>
__global__ __launch_bounds__(256, 2) void crf_chain_kernel(
    const float* __restrict__ feats,
    const float* __restrict__ trans,
    const int*   __restrict__ targets,
    const __fp16* __restrict__ efeat,
    float*       __restrict__ out)
{
    const int t = threadIdx.x;
    const int w = t >> 6, l = t & 63;
    const int c = l & 15, h = l >> 4;
    const int base = blockIdx.x * 32;
    const int bb = (w & 1) * 16 + c;          // block-local batch 0..31
    const int batch = base + bb;
    const bool isFwd = (w >> 1) == 0;
    const int side = isFwd ? 0 : 1;

    __shared__ __align__(16) float AB[2][32][TT];   // final log2-states
    __shared__ float salpha[32];
    __shared__ float gpart[32][8];

    // ---- E fragments: A[row=16tt+c][k(q,h,j)] ----
    f16x8 E[8][4];
#pragma unroll
    for (int tt = 0; tt < 8; ++tt) {
        const int ro = 16 * tt + c;
#pragma unroll
        for (int q = 0; q < 4; ++q) {
            f16x8 F;
            if (isFwd) {
                f32x4 t0 = *(const f32x4*)(trans + ro * TT + 32 * q + 4 * h);
                f32x4 t1 = *(const f32x4*)(trans + ro * TT + 32 * q + 16 + 4 * h);
#pragma unroll
                for (int j = 0; j < 4; ++j) {
                    F[j]     = (__fp16)exn(t0[j]);
                    F[j + 4] = (__fp16)exn(t1[j]);
                }
            } else {
#pragma unroll
                for (int j = 0; j < 8; ++j) {
                    const int k = 32 * q + ((j & 4) << 2) + 4 * h + (j & 3);
                    F[j] = (__fp16)exn(trans[k * TT + ro]);   // E^T
                }
            }
            E[tt][q] = F;
        }
    }

    // ---- seed B (same k-map) + its per-column max (lag-1 init) ----
    f16x8 Bv[4];
    float smax = 0.f;
#pragma unroll
    for (int q = 0; q < 4; ++q) {
#pragma unroll
        for (int j = 0; j < 8; ++j) {
            const int k = 32 * q + ((j & 4) << 2) + 4 * h + (j & 3);
            float v;
            if (isFwd) v = (k == START_TAG) ? 1.f : 0.f;
            else       v = exn(trans[STOP_TAG * TT + k] +
                               feats[((size_t)batch * SS + 511) * TT + k]);
            smax = fmaxf(smax, v);
            Bv[q][j] = (__fp16)v;
        }
    }
    smax = fmaxf(smax, __shfl_xor(smax, 16));
    smax = fmaxf(smax, __shfl_xor(smax, 32));
    float mprev = smax;

    // ---- emission pointer ----
    const char* pef;
    int sstep;
    if constexpr (PRE) {
        pef = (const char*)efeat + 2 * (((size_t)batch * SS + (isFwd ? 0 : 510)) * TT) + 8 * h;
        sstep = isFwd ? (TT * 2) : -(TT * 2);
    } else {
        pef = (const char*)feats + 4 * (((size_t)batch * SS + (isFwd ? 0 : 510)) * TT) + 16 * h;
        sstep = isFwd ? (TT * 4) : -(TT * 4);
    }

    int Mint = 0;
    u32x2 e0[8], e1[8], e2[8];
    load_ef<PRE>(pef, sstep, e0);             // pos 0 (fwd) / 510 (bwd)
    load_ef<PRE>(pef, sstep, e1);
    load_ef<PRE>(pef, sstep, e2);
#pragma unroll 1
    for (int it = 0; it < 84; ++it) {         // steps 0..251, loads 3..254
        chain_step(E, Bv, e0, Mint, mprev); load_ef<PRE>(pef, sstep, e0);
        chain_step(E, Bv, e1, Mint, mprev); load_ef<PRE>(pef, sstep, e1);
        chain_step(E, Bv, e2, Mint, mprev); load_ef<PRE>(pef, sstep, e2);
    }
    chain_step(E, Bv, e0, Mint, mprev); load_ef<PRE>(pef, sstep, e0);  // step 252, load ef[255]
    chain_step(E, Bv, e1, Mint, mprev);                                 // 253
    chain_step(E, Bv, e2, Mint, mprev);                                 // 254
    // 255th multiply = epilogue (fwd folds ef_255 in log space; bwd none)

    const f32x4 z = {0.f, 0.f, 0.f, 0.f};
    f32x4 acc[8];
#pragma unroll
    for (int tt = 0; tt < 8; ++tt)
        acc[tt] = __builtin_amdgcn_mfma_f32_16x16x32_f16(E[tt][0], Bv[0], z, 0, 0, 0);
#pragma unroll
    for (int q = 1; q < 4; ++q)
#pragma unroll
        for (int tt = 0; tt < 8; ++tt)
            acc[tt] = __builtin_amdgcn_mfma_f32_16x16x32_f16(E[tt][q], Bv[q], acc[tt], 0, 0, 0);

    const float Mtotf = (float)Mint;
#pragma unroll
    for (int tt = 0; tt < 8; ++tt) {
        float ev0 = 1.f, ev1 = 1.f, ev2 = 1.f, ev3 = 1.f;
        if (isFwd) {
            h2 a = __builtin_bit_cast(h2, e0[tt][0]);   // ef[255]
            h2 b = __builtin_bit_cast(h2, e0[tt][1]);
            ev0 = (float)a[0]; ev1 = (float)a[1]; ev2 = (float)b[0]; ev3 = (float)b[1];
        }
        f32x4 v;
        v[0] = Mtotf + lg2(fmaxf(acc[tt][0] * ev0, 1e-35f));
        v[1] = Mtotf + lg2(fmaxf(acc[tt][1] * ev1, 1e-35f));
        v[2] = Mtotf + lg2(fmaxf(acc[tt][2] * ev2, 1e-35f));
        v[3] = Mtotf + lg2(fmaxf(acc[tt][3] * ev3, 1e-35f));
        *(f32x4*)&AB[side][bb][16 * tt + 4 * h] = v;   // D rows are true tag indices
    }
    __syncthreads();

    // ---- Z = LSE_tag(A + B) (log2 domain), 8 batches per wave ----
#pragma unroll 1
    for (int k8 = 0; k8 < 8; ++k8) {
        const int bq = w * 8 + k8;
        float v0 = AB[0][bq][l] + AB[1][bq][l];
        float v1 = AB[0][bq][l + 64] + AB[1][bq][l + 64];
        float mm = wave_max(fmaxf(v0, v1));
        float ss = wave_sum(ex2(v0 - mm) + ex2(v1 - mm));
        if (l == 0) salpha[bq] = (mm + lg2(ss)) * LN2;
    }

    // ---- gold path score: 8 threads per batch, 64 steps each ----
    {
        const int bbg = t & 31, ck = t >> 5;
        const int gb  = base + bbg;
        const int* tg = targets + gb * SS;
        const float* fb = feats + (size_t)gb * SS * TT;
        float gs = 0.f;
        const int i0 = ck * 64;
        int prev = (i0 == 0) ? START_TAG : tg[i0 - 1];
        for (int i = i0; i < i0 + 64; ++i) {
            int cur = tg[i];
            gs += trans[cur * TT + prev] + fb[(size_t)i * TT + cur];
            prev = cur;
        }
        if (ck == 7) gs += trans[STOP_TAG * TT + tg[SS - 1]];
        gpart[bbg][ck] = gs;
    }
    __syncthreads();

    if (t < 32) {
        float g = 0.f;
#pragma unroll
        for (int k = 0; k < 8; ++k) g += gpart[t][k];
        out[base + t] = g - salpha[t];
    }
}

extern "C" void kernel_launch(void* const* d_in, const int* in_sizes, int n_in,
                              void* d_out, int out_size, void* d_ws, size_t ws_size,
                              hipStream_t stream) {
    (void)in_sizes; (void)n_in; (void)out_size;
    const float* feats   = (const float*)d_in[0];
    const float* trans   = (const float*)d_in[1];
    const int*   targets = (const int*)d_in[2];
    float*       out     = (float*)d_out;

    const size_t efbytes = (size_t)256 * SS * TT * sizeof(__fp16);  // 33.5 MB
    if (d_ws && ws_size >= efbytes) {
        __fp16* ef = (__fp16*)d_ws;
        exp_feats_kernel<<<dim3(8192), dim3(256), 0, stream>>>(feats, ef);
        crf_chain_kernel<true><<<dim3(8), dim3(256), 0, stream>>>(feats, trans, targets, ef, out);
    } else {
        crf_chain_kernel<false><<<dim3(8), dim3(256), 0, stream>>>(feats, trans, targets,
                                                                   (const __fp16*)nullptr, out);
    }
}

// Round 6
// 348.559 us; speedup vs baseline: 1.1883x; 1.1883x over previous
//
#include <hip/hip_runtime.h>

#define TT 128
#define SS 512
#define START_TAG 126
#define STOP_TAG 127
#define LOG2E 1.4426950408889634f
#define LN2   0.6931471805599453f
#define CBITS 8

typedef float f32x4 __attribute__((ext_vector_type(4)));
typedef unsigned int u32;
typedef unsigned int u32x2 __attribute__((ext_vector_type(2)));

__device__ __forceinline__ float ex2(float x){ return __builtin_amdgcn_exp2f(x); }   // 2^x
__device__ __forceinline__ float lg2(float x){ return __builtin_amdgcn_logf(x); }    // log2
__device__ __forceinline__ float exn(float x){ return __builtin_amdgcn_exp2f(x*LOG2E); } // e^x
__device__ __forceinline__ long mk64(u32 lo, u32 hi){ u32x2 v = {lo, hi}; return __builtin_bit_cast(long, v); }
template<bool HI>
__device__ __forceinline__ u32 pk8(float a, float b, u32 old){
    return (u32)__builtin_amdgcn_cvt_pk_fp8_f32(a, b, (int)old, HI);   // HI must be imm
}
__device__ __forceinline__ float wave_max(float v) {
#pragma unroll
    for (int off = 32; off >= 1; off >>= 1) v = fmaxf(v, __shfl_xor(v, off));
    return v;
}
__device__ __forceinline__ float wave_sum(float v) {
#pragma unroll
    for (int off = 32; off >= 1; off >>= 1) v += __shfl_xor(v, off);
    return v;
}

// E fragment builders (init-time only). k-map: k(q,h,j) = 32q + 16*(j>=4) + 4h + (j&3)
__device__ __forceinline__ long efrag_f(const float* p) {        // fwd: rows contiguous
    f32x4 a = *(const f32x4*)p;
    f32x4 b = *(const f32x4*)(p + 16);
    u32 lo = pk8<false>(exn(a[0]), exn(a[1]), 0); lo = pk8<true>(exn(a[2]), exn(a[3]), lo);
    u32 hi = pk8<false>(exn(b[0]), exn(b[1]), 0); hi = pk8<true>(exn(b[2]), exn(b[3]), hi);
    return mk64(lo, hi);
}
__device__ __forceinline__ long efrag_b(const float* p) {        // bwd: E^T, stride-TT
    u32 lo = pk8<false>(exn(p[0]), exn(p[TT]), 0); lo = pk8<true>(exn(p[2*TT]), exn(p[3*TT]), lo);
    const float* q = p + 16 * TT;
    u32 hi = pk8<false>(exn(q[0]), exn(q[TT]), 0); hi = pk8<true>(exn(q[2*TT]), exn(q[3*TT]), hi);
    return mk64(lo, hi);
}

// ---- macro lists: everything in the hot loop is a NAMED scalar (no C-arrays;
// R3/R4 showed LLVM parks arrays in the AGPR half -> accvgpr churn, 6x VALU). ----
#define T8(M)    M(0) M(1) M(2) M(3) M(4) M(5) M(6) M(7)
#define T8P(M,P) M(0,P) M(1,P) M(2,P) M(3,P) M(4,P) M(5,P) M(6,P) M(7,P)

#define DECLE(t) long E0##t, E1##t, E2##t, E3##t;
#define DECLR(t) f32x4 R##t;
#define DECLQ(t) f32x4 Q##t;
#define DECLS(t) f32x4 S##t;

#define MFQ0(t) A##t = __builtin_amdgcn_mfma_f32_16x16x32_fp8_fp8(E0##t, B0, vz,    0, 0, 0);
#define MFQ1(t) A##t = __builtin_amdgcn_mfma_f32_16x16x32_fp8_fp8(E1##t, B1, A##t, 0, 0, 0);
#define MFQ2(t) A##t = __builtin_amdgcn_mfma_f32_16x16x32_fp8_fp8(E2##t, B2, A##t, 0, 0, 0);
#define MFQ3(t) A##t = __builtin_amdgcn_mfma_f32_16x16x32_fp8_fp8(E3##t, B3, A##t, 0, 0, 0);

// emission*scale folded: e = 2^(feat*LOG2E - s) = exp(feat) * 2^-s  (exact fold)
#define PACKT(t, RR) { \
    f32x4 e, d = A##t; \
    e[0] = ex2(__builtin_fmaf(RR##t[0], LOG2E, msF)); \
    e[1] = ex2(__builtin_fmaf(RR##t[1], LOG2E, msF)); \
    e[2] = ex2(__builtin_fmaf(RR##t[2], LOG2E, msF)); \
    e[3] = ex2(__builtin_fmaf(RR##t[3], LOG2E, msF)); \
    d[0] *= e[0]; d[1] *= e[1]; d[2] *= e[2]; d[3] *= e[3]; \
    mloc = fmaxf(fmaxf(mloc, fmaxf(d[0], d[1])), fmaxf(d[2], d[3])); \
    u32 r_ = pk8<false>(d[0], d[1], 0); \
    P##t = pk8<true>(d[2], d[3], r_); }

#define LDRT(t, RR) RR##t = *(const f32x4*)(pef + 64 * (t));

// One recurrence step for 16 chains. Scale 2^-s from LAG-1 post-scale colmax
// (stable: m_i = g_i - C, no feedback recurrence; validated R3/R4). Integer-exact
// bookkeeping in Mint. Uses buffer RR, reloads RR for use 2 steps later.
#define MSTEP(RR) { \
    f32x4 vz = {0.f, 0.f, 0.f, 0.f}; \
    f32x4 A0, A1, A2, A3, A4, A5, A6, A7; \
    T8(MFQ0) T8(MFQ1) T8(MFQ2) T8(MFQ3) \
    int s_ = ((__float_as_int(fmaxf(mprev, 1e-30f)) >> 23) & 255) - 126 + CBITS; \
    s_ = s_ < -120 ? -120 : (s_ > 120 ? 120 : s_); \
    Mint += s_; \
    const float msF = -(float)s_; \
    float mloc = 0.f; \
    u32 P0, P1, P2, P3, P4, P5, P6, P7; \
    T8P(PACKT, RR) \
    B0 = mk64(P0, P1); B1 = mk64(P2, P3); B2 = mk64(P4, P5); B3 = mk64(P6, P7); \
    T8P(LDRT, RR) pef += sstep; \
    mloc = fmaxf(mloc, __shfl_xor(mloc, 16)); \
    mloc = fmaxf(mloc, __shfl_xor(mloc, 32)); \
    mprev = mloc; }

#define EINF(t) { const float* rp = trans + (16*(t) + c) * TT + 4 * h; \
    E0##t = efrag_f(rp); E1##t = efrag_f(rp + 32); E2##t = efrag_f(rp + 64); E3##t = efrag_f(rp + 96); }
#define EINB(t) { const float* cp = trans + (16*(t) + c) + (4 * h) * TT; \
    E0##t = efrag_b(cp); E1##t = efrag_b(cp + 32*TT); E2##t = efrag_b(cp + 64*TT); E3##t = efrag_b(cp + 96*TT); }

#define SEEDF(t) S##t = (f32x4){0.f, 0.f, 0.f, 0.f};
#define SEEDB(t) { \
    f32x4 tr4 = *(const f32x4*)(trans + STOP_TAG * TT + 16*(t) + 4*h); \
    f32x4 fe4 = *(const f32x4*)(feats + f511 + 16*(t) + 4*h); \
    S##t[0] = exn(tr4[0] + fe4[0]); S##t[1] = exn(tr4[1] + fe4[1]); \
    S##t[2] = exn(tr4[2] + fe4[2]); S##t[3] = exn(tr4[3] + fe4[3]); }
#define SMXT(t) smax = fmaxf(smax, fmaxf(fmaxf(S##t[0], S##t[1]), fmaxf(S##t[2], S##t[3])));
#define SPKT(t) { u32 r_ = pk8<false>(S##t[0]*sc0, S##t[1]*sc0, 0); \
    P##t = pk8<true>(S##t[2]*sc0, S##t[3]*sc0, r_); }

#define EPIT(t) { f32x4 v; \
    float e0 = 1.f, e1 = 1.f, e2 = 1.f, e3 = 1.f; \
    if (isFwd) { e0 = exn(Q##t[0]); e1 = exn(Q##t[1]); e2 = exn(Q##t[2]); e3 = exn(Q##t[3]); } \
    v[0] = Mtotf + lg2(fmaxf(A##t[0] * e0, 1e-35f)); \
    v[1] = Mtotf + lg2(fmaxf(A##t[1] * e1, 1e-35f)); \
    v[2] = Mtotf + lg2(fmaxf(A##t[2] * e2, 1e-35f)); \
    v[3] = Mtotf + lg2(fmaxf(A##t[3] * e3, 1e-35f)); \
    *(f32x4*)&AB[side][bb][16*(t) + 4*h] = v; }

// 8 blocks x 256 threads. Block k: batches 32k..32k+31.
//  w0: fwd chains (batches +0..15)  w1: fwd (+16..31)
//  w2: bwd chains (+0..15)          w3: bwd (+16..31)
__global__ __launch_bounds__(256, 2) void crf_chain_kernel(
    const float* __restrict__ feats,
    const float* __restrict__ trans,
    const int*   __restrict__ targets,
    float*       __restrict__ out)
{
    const int t = threadIdx.x;
    const int w = t >> 6, l = t & 63;
    const int c = l & 15, h = l >> 4;
    const int base = blockIdx.x * 32;
    const int bb = (w & 1) * 16 + c;          // block-local batch 0..31
    const int batch = base + bb;
    const bool isFwd = (w >> 1) == 0;
    const int side = isFwd ? 0 : 1;

    __shared__ __align__(16) float AB[2][32][TT];   // final log2-states
    __shared__ float salpha[32];
    __shared__ float gpart[32][8];

    // ---- E fragments (fp8, named): A[row=16t+c][k(q,h,j)] ----
    T8(DECLE)
    if (isFwd) { T8(EINF) } else { T8(EINB) }

    // ---- seed B (same k-map), exact pow2 pre-normalize (fp8 sat guard) ----
    T8(DECLS)
    const size_t f511 = ((size_t)batch * SS + 511) * TT;
    if (isFwd) { T8(SEEDF) if (h == 3) S7[2] = 1.0f; }   // k=126 -> t=7,h=3,j=2
    else       { T8(SEEDB) }
    float smax = 0.f;
    T8(SMXT)
    smax = fmaxf(smax, __shfl_xor(smax, 16));
    smax = fmaxf(smax, __shfl_xor(smax, 32));
    int Mint = ((__float_as_int(fmaxf(smax, 1e-30f)) >> 23) & 255) - 126;
    const float sc0 = __int_as_float((127 - Mint) << 23);   // exact 2^-s0
    float mprev = smax * sc0;                                // in (0.5, 1]
    long B0, B1, B2, B3;
    {
        u32 P0, P1, P2, P3, P4, P5, P6, P7;
        T8(SPKT)
        B0 = mk64(P0, P1); B1 = mk64(P2, P3); B2 = mk64(P4, P5); B3 = mk64(P6, P7);
    }

    // ---- feats pointers + double-buffered raw-f32 staging (named regs) ----
    const char* pef = (const char*)feats +
        4 * (((size_t)batch * SS + (isFwd ? 0 : 510)) * TT + 4 * h);
    const int sstep = isFwd ? (TT * 4) : -(TT * 4);
    T8(DECLR) T8(DECLQ)
    T8P(LDRT, R) pef += sstep;    // pos 0 / 510
    T8P(LDRT, Q) pef += sstep;    // pos 1 / 509

#pragma unroll 1
    for (int it = 0; it < 127; ++it) {        // steps 0..253
        MSTEP(R)
        MSTEP(Q)
    }
    MSTEP(R)                                   // step 254 (reload harmless)
    // step 255 = epilogue multiply; fwd folds ef[255] (in Q) post-log; bwd none.

    const float Mtotf = (float)Mint;
    {
        f32x4 vz = {0.f, 0.f, 0.f, 0.f};
        f32x4 A0, A1, A2, A3, A4, A5, A6, A7;
        T8(MFQ0) T8(MFQ1) T8(MFQ2) T8(MFQ3)
        T8(EPIT)                                // D rows are true tag indices
    }
    __syncthreads();

    // ---- Z = LSE_tag(A + B) (log2 domain), 8 batches per wave ----
#pragma unroll 1
    for (int k8 = 0; k8 < 8; ++k8) {
        const int bq = w * 8 + k8;
        float v0 = AB[0][bq][l] + AB[1][bq][l];
        float v1 = AB[0][bq][l + 64] + AB[1][bq][l + 64];
        float mm = wave_max(fmaxf(v0, v1));
        float ss = wave_sum(ex2(v0 - mm) + ex2(v1 - mm));
        if (l == 0) salpha[bq] = (mm + lg2(ss)) * LN2;
    }

    // ---- gold path score: 8 threads per batch, 64 steps each ----
    {
        const int bbg = t & 31, ck = t >> 5;
        const int gb  = base + bbg;
        const int* tg = targets + gb * SS;
        const float* fb = feats + (size_t)gb * SS * TT;
        float gs = 0.f;
        const int i0 = ck * 64;
        int prev = (i0 == 0) ? START_TAG : tg[i0 - 1];
        for (int i = i0; i < i0 + 64; ++i) {
            int cur = tg[i];
            gs += trans[cur * TT + prev] + fb[(size_t)i * TT + cur];
            prev = cur;
        }
        if (ck == 7) gs += trans[STOP_TAG * TT + tg[SS - 1]];
        gpart[bbg][ck] = gs;
    }
    __syncthreads();

    if (t < 32) {
        float g = 0.f;
#pragma unroll
        for (int k = 0; k < 8; ++k) g += gpart[t][k];
        out[base + t] = g - salpha[t];
    }
}

extern "C" void kernel_launch(void* const* d_in, const int* in_sizes, int n_in,
                              void* d_out, int out_size, void* d_ws, size_t ws_size,
                              hipStream_t stream) {
    (void)in_sizes; (void)n_in; (void)out_size; (void)d_ws; (void)ws_size;
    const float* feats   = (const float*)d_in[0];
    const float* trans   = (const float*)d_in[1];
    const int*   targets = (const int*)d_in[2];
    float*       out     = (float*)d_out;
    crf_chain_kernel<<<dim3(8), dim3(256), 0, stream>>>(feats, trans, targets, out);
}